// Round 1
// baseline (822.037 us; speedup 1.0000x reference)
//
#include <hip/hip_runtime.h>

#define N_NODES 100000
#define N_EDGES 1600000
#define D_IN 32
#define D_OUT 64

// Edge-parallel SpMM scatter: one thread per (edge, feature-dim).
// xout[row[e], d] += val[e] * xin[col[e], d]
__global__ void spmm_scatter(const int* __restrict__ erow,
                             const int* __restrict__ ecol,
                             const float* __restrict__ eval_,
                             const float* __restrict__ xin,
                             float* __restrict__ xout) {
    long long tid = (long long)blockIdx.x * blockDim.x + threadIdx.x;
    const long long total = (long long)N_EDGES * D_IN;
    if (tid >= total) return;
    int e = (int)(tid >> 5);   // tid / 32  (D_IN == 32)
    int d = (int)(tid & 31);   // tid % 32
    int r = erow[e];
    int c = ecol[e];
    float v = eval_[e];
    float g = v * xin[(long long)c * D_IN + d];
    atomicAdd(&xout[(long long)r * D_IN + d], g);
}

// out[i, :] = xin[i, :] @ W + b   — W/b staged in LDS, 4 rows x 64 cols per block
__global__ void linear_bias(const float* __restrict__ xin,
                            const float* __restrict__ W,
                            const float* __restrict__ b,
                            float* __restrict__ out) {
    __shared__ float sW[D_IN * D_OUT];
    __shared__ float sb[D_OUT];
    for (int i = threadIdx.x; i < D_IN * D_OUT; i += blockDim.x) sW[i] = W[i];
    if (threadIdx.x < D_OUT) sb[threadIdx.x] = b[threadIdx.x];
    __syncthreads();

    const int rows_per_block = 256 / D_OUT;  // 4
    int r = blockIdx.x * rows_per_block + (threadIdx.x / D_OUT);
    int j = threadIdx.x % D_OUT;
    if (r >= N_NODES) return;

    const float* xr = xin + (long long)r * D_IN;
    float acc = sb[j];
#pragma unroll
    for (int d = 0; d < D_IN; ++d) {
        acc += xr[d] * sW[d * D_OUT + j];
    }
    out[(long long)r * D_OUT + j] = acc;
}

extern "C" void kernel_launch(void* const* d_in, const int* in_sizes, int n_in,
                              void* d_out, int out_size, void* d_ws, size_t ws_size,
                              hipStream_t stream) {
    const float* x     = (const float*)d_in[0];
    const int*   erow  = (const int*)d_in[1];
    const int*   ecol  = (const int*)d_in[2];
    const float* eval_ = (const float*)d_in[3];
    const float* W     = (const float*)d_in[4];
    const float* b     = (const float*)d_in[5];
    // d_in[6] is k; static Python int == 4 in setup_inputs, hard-coded below
    float* out = (float*)d_out;

    const size_t feat_elems = (size_t)N_NODES * D_IN;
    float* buf0 = (float*)d_ws;
    float* buf1 = buf0 + feat_elems;

    const float* cur = x;
    const long long total = (long long)N_EDGES * D_IN;  // 51.2M
    const int threads = 256;
    const int blocks = (int)((total + threads - 1) / threads);

    for (int hop = 0; hop < 4; ++hop) {
        float* dst = (hop & 1) ? buf1 : buf0;
        hipMemsetAsync(dst, 0, feat_elems * sizeof(float), stream);
        spmm_scatter<<<blocks, threads, 0, stream>>>(erow, ecol, eval_, cur, dst);
        cur = dst;
    }

    const int lin_blocks = (N_NODES + 3) / 4;  // 4 rows per block
    linear_bias<<<lin_blocks, 256, 0, stream>>>(cur, W, b, out);
}

// Round 2
// 744.342 us; speedup vs baseline: 1.1044x; 1.1044x over previous
//
#include <hip/hip_runtime.h>

#define N_NODES 100000
#define N_EDGES 1600000
#define D_IN 32
#define D_OUT 64

// ---------------- CSR build (once per call; edges are re-read each call) ----

__global__ void count_rows(const int* __restrict__ erow, int* __restrict__ counts) {
    int e = blockIdx.x * blockDim.x + threadIdx.x;
    if (e < N_EDGES) atomicAdd(&counts[erow[e]], 1);
}

// Single-block exclusive scan over 100k counts -> row_ptr[0..N], plus cursor copy.
__global__ void scan_rowptr(const int* __restrict__ counts,
                            int* __restrict__ row_ptr,
                            int* __restrict__ cursor) {
    __shared__ int partials[1024];
    const int T = 1024;
    int t = threadIdx.x;
    const int chunk = (N_NODES + T - 1) / T;  // 98
    int start = t * chunk;
    int end = start + chunk; if (end > N_NODES) end = N_NODES;
    int sum = 0;
    for (int i = start; i < end; ++i) sum += counts[i];
    partials[t] = sum;
    __syncthreads();
    // Hillis-Steele inclusive scan over 1024 partials
    for (int off = 1; off < T; off <<= 1) {
        int v = 0;
        if (t >= off) v = partials[t - off];
        __syncthreads();
        if (t >= off) partials[t] += v;
        __syncthreads();
    }
    int run = (t == 0) ? 0 : partials[t - 1];
    for (int i = start; i < end; ++i) {
        row_ptr[i] = run;
        cursor[i] = run;
        run += counts[i];
    }
    if (t == T - 1) row_ptr[N_NODES] = run;  // == N_EDGES
}

__global__ void build_csr(const int* __restrict__ erow,
                          const int* __restrict__ ecol,
                          const float* __restrict__ eval_,
                          int* __restrict__ cursor,
                          int* __restrict__ scol,
                          float* __restrict__ sval) {
    int e = blockIdx.x * blockDim.x + threadIdx.x;
    if (e < N_EDGES) {
        int r = erow[e];
        int pos = atomicAdd(&cursor[r], 1);
        scol[pos] = ecol[e];
        sval[pos] = eval_[e];
    }
}

// ---------------- Row-gather SpMM: 32 lanes per row, acc in registers -------
// xout[r, 0:32] = sum_{e in row r} sval[e] * xin[scol[e], 0:32]
__global__ void spmm_csr(const int* __restrict__ row_ptr,
                         const int* __restrict__ scol,
                         const float* __restrict__ sval,
                         const float* __restrict__ xin,
                         float* __restrict__ xout) {
    int lane = threadIdx.x & 31;
    int r = (blockIdx.x * blockDim.x + threadIdx.x) >> 5;
    if (r >= N_NODES) return;
    int p0 = row_ptr[r];
    int p1 = row_ptr[r + 1];
    float acc = 0.f;
    int e = p0;
    for (; e + 2 <= p1; e += 2) {  // 2-edge unroll for ILP
        int   c0 = scol[e],     c1 = scol[e + 1];
        float v0 = sval[e],     v1 = sval[e + 1];
        acc += v0 * xin[c0 * D_IN + lane];
        acc += v1 * xin[c1 * D_IN + lane];
    }
    if (e < p1) acc += sval[e] * xin[scol[e] * D_IN + lane];
    xout[r * D_IN + lane] = acc;
}

// ---------------- Final dense linear: out = x @ W + b -----------------------
__global__ void linear_bias(const float* __restrict__ xin,
                            const float* __restrict__ W,
                            const float* __restrict__ b,
                            float* __restrict__ out) {
    __shared__ float sW[D_IN * D_OUT];
    __shared__ float sb[D_OUT];
    for (int i = threadIdx.x; i < D_IN * D_OUT; i += blockDim.x) sW[i] = W[i];
    if (threadIdx.x < D_OUT) sb[threadIdx.x] = b[threadIdx.x];
    __syncthreads();

    int r = blockIdx.x * 4 + (threadIdx.x >> 6);  // 4 rows/block, 64 threads/row
    int j = threadIdx.x & 63;
    if (r >= N_NODES) return;

    const float* xr = xin + r * D_IN;
    float acc = sb[j];
#pragma unroll
    for (int d = 0; d < D_IN; ++d) acc += xr[d] * sW[d * D_OUT + j];
    out[r * D_OUT + j] = acc;
}

extern "C" void kernel_launch(void* const* d_in, const int* in_sizes, int n_in,
                              void* d_out, int out_size, void* d_ws, size_t ws_size,
                              hipStream_t stream) {
    const float* x     = (const float*)d_in[0];
    const int*   erow  = (const int*)d_in[1];
    const int*   ecol  = (const int*)d_in[2];
    const float* eval_ = (const float*)d_in[3];
    const float* W     = (const float*)d_in[4];
    const float* b     = (const float*)d_in[5];
    // d_in[6] is k (static Python int == 4) — hop count hard-coded below
    float* out = (float*)d_out;

    // Workspace layout (elements of 4 B):
    //   buf0[3.2M] | buf1[3.2M] | counts[100000] | row_ptr[100004] |
    //   cursor[100000] | scol[1.6M] | sval[1.6M]           total ~39.6 MB
    float* buf0    = (float*)d_ws;
    float* buf1    = buf0 + (size_t)N_NODES * D_IN;
    int*   counts  = (int*)(buf1 + (size_t)N_NODES * D_IN);
    int*   row_ptr = counts + N_NODES;
    int*   cursor  = row_ptr + (N_NODES + 4);
    int*   scol    = cursor + N_NODES;
    float* sval    = (float*)(scol + N_EDGES);

    const int threads = 256;
    const int eblocks = (N_EDGES + threads - 1) / threads;

    // --- CSR build ---
    hipMemsetAsync(counts, 0, N_NODES * sizeof(int), stream);
    count_rows<<<eblocks, threads, 0, stream>>>(erow, counts);
    scan_rowptr<<<1, 1024, 0, stream>>>(counts, row_ptr, cursor);
    build_csr<<<eblocks, threads, 0, stream>>>(erow, ecol, eval_, cursor, scol, sval);

    // --- 4 hops of row-gather SpMM (ping-pong) ---
    const int rows_per_block = threads / 32;  // 8
    const int sblocks = (N_NODES + rows_per_block - 1) / rows_per_block;
    const float* cur = x;
    for (int hop = 0; hop < 4; ++hop) {
        float* dst = (hop & 1) ? buf1 : buf0;
        spmm_csr<<<sblocks, threads, 0, stream>>>(row_ptr, scol, sval, cur, dst);
        cur = dst;
    }

    // --- final linear ---
    const int lin_blocks = (N_NODES + 3) / 4;
    linear_bias<<<lin_blocks, 256, 0, stream>>>(cur, W, b, out);
}

// Round 3
// 480.276 us; speedup vs baseline: 1.7116x; 1.5498x over previous
//
#include <hip/hip_runtime.h>

#define N_NODES 100000
#define N_EDGES 1600000
#define D_IN 32
#define D_OUT 64

#define SCAN_T 1024
#define SCAN_BLOCKS ((N_NODES + SCAN_T - 1) / SCAN_T)  // 98

// ---------------- CSR build (every call; d_ws is re-poisoned each launch) ---

__global__ void count_rows(const int* __restrict__ erow, int* __restrict__ counts) {
    int e = blockIdx.x * blockDim.x + threadIdx.x;
    if (e < N_EDGES) atomicAdd(&counts[erow[e]], 1);
}

// Pass 1: per-block sums of counts (98 blocks x 1024)
__global__ void block_reduce(const int* __restrict__ counts, int* __restrict__ blocksums) {
    __shared__ int sdata[SCAN_T];
    int i = blockIdx.x * SCAN_T + threadIdx.x;
    sdata[threadIdx.x] = (i < N_NODES) ? counts[i] : 0;
    __syncthreads();
    for (int s = SCAN_T / 2; s > 0; s >>= 1) {
        if (threadIdx.x < s) sdata[threadIdx.x] += sdata[threadIdx.x + s];
        __syncthreads();
    }
    if (threadIdx.x == 0) blocksums[blockIdx.x] = sdata[0];
}

// Pass 2: exclusive scan of the 98 block sums (single tiny block)
__global__ void scan_blocksums(int* __restrict__ blocksums) {
    __shared__ int s[128];
    int t = threadIdx.x;
    s[t] = (t < SCAN_BLOCKS) ? blocksums[t] : 0;
    __syncthreads();
    for (int off = 1; off < 128; off <<= 1) {
        int v = 0;
        if (t >= off) v = s[t - off];
        __syncthreads();
        if (t >= off) s[t] += v;
        __syncthreads();
    }
    if (t < SCAN_BLOCKS) blocksums[t] = (t == 0) ? 0 : s[t - 1];
}

// Pass 3: block-local scan + block offset -> row_ptr, cursor
__global__ void fill_rowptr(const int* __restrict__ counts,
                            const int* __restrict__ blockoffs,
                            int* __restrict__ row_ptr,
                            int* __restrict__ cursor) {
    __shared__ int s[SCAN_T];
    int t = threadIdx.x;
    int i = blockIdx.x * SCAN_T + t;
    s[t] = (i < N_NODES) ? counts[i] : 0;
    __syncthreads();
    for (int off = 1; off < SCAN_T; off <<= 1) {
        int v = 0;
        if (t >= off) v = s[t - off];
        __syncthreads();
        if (t >= off) s[t] += v;
        __syncthreads();
    }
    int excl = blockoffs[blockIdx.x] + ((t == 0) ? 0 : s[t - 1]);
    if (i < N_NODES) { row_ptr[i] = excl; cursor[i] = excl; }
    if (i == N_NODES - 1) row_ptr[N_NODES] = N_EDGES;
}

// Scatter edges into CSR order; payload packed as {col, val} in one int2
__global__ void build_csr(const int* __restrict__ erow,
                          const int* __restrict__ ecol,
                          const float* __restrict__ eval_,
                          int* __restrict__ cursor,
                          int2* __restrict__ epack) {
    int e = blockIdx.x * blockDim.x + threadIdx.x;
    if (e < N_EDGES) {
        int r = erow[e];
        int pos = atomicAdd(&cursor[r], 1);
        int2 p;
        p.x = ecol[e];
        p.y = __float_as_int(eval_[e]);
        epack[pos] = p;
    }
}

// ---------------- Row-gather SpMM: 32 lanes per row, acc in registers -------
__global__ void spmm_csr(const int* __restrict__ row_ptr,
                         const int2* __restrict__ epack,
                         const float* __restrict__ xin,
                         float* __restrict__ xout) {
    int lane = threadIdx.x & 31;
    int r = (blockIdx.x * blockDim.x + threadIdx.x) >> 5;
    if (r >= N_NODES) return;
    int p0 = row_ptr[r];
    int p1 = row_ptr[r + 1];
    float acc = 0.f;
    int e = p0;
    for (; e + 4 <= p1; e += 4) {  // 4-edge unroll: 4 outstanding gathers
        int2 q0 = epack[e], q1 = epack[e + 1], q2 = epack[e + 2], q3 = epack[e + 3];
        acc += __int_as_float(q0.y) * xin[q0.x * D_IN + lane];
        acc += __int_as_float(q1.y) * xin[q1.x * D_IN + lane];
        acc += __int_as_float(q2.y) * xin[q2.x * D_IN + lane];
        acc += __int_as_float(q3.y) * xin[q3.x * D_IN + lane];
    }
    for (; e < p1; ++e) {
        int2 q = epack[e];
        acc += __int_as_float(q.y) * xin[q.x * D_IN + lane];
    }
    xout[r * D_IN + lane] = acc;
}

// ---------------- Final dense linear: out = x @ W + b -----------------------
__global__ void linear_bias(const float* __restrict__ xin,
                            const float* __restrict__ W,
                            const float* __restrict__ b,
                            float* __restrict__ out) {
    __shared__ float sW[D_IN * D_OUT];
    __shared__ float sb[D_OUT];
    for (int i = threadIdx.x; i < D_IN * D_OUT; i += blockDim.x) sW[i] = W[i];
    if (threadIdx.x < D_OUT) sb[threadIdx.x] = b[threadIdx.x];
    __syncthreads();

    int r = blockIdx.x * 4 + (threadIdx.x >> 6);  // 4 rows/block, 64 threads/row
    int j = threadIdx.x & 63;
    if (r >= N_NODES) return;

    const float* xr = xin + r * D_IN;
    float acc = sb[j];
#pragma unroll
    for (int d = 0; d < D_IN; ++d) acc += xr[d] * sW[d * D_OUT + j];
    out[r * D_OUT + j] = acc;
}

extern "C" void kernel_launch(void* const* d_in, const int* in_sizes, int n_in,
                              void* d_out, int out_size, void* d_ws, size_t ws_size,
                              hipStream_t stream) {
    const float* x     = (const float*)d_in[0];
    const int*   erow  = (const int*)d_in[1];
    const int*   ecol  = (const int*)d_in[2];
    const float* eval_ = (const float*)d_in[3];
    const float* W     = (const float*)d_in[4];
    const float* b     = (const float*)d_in[5];
    // d_in[6] is k (static Python int == 4) — hop count hard-coded below
    float* out = (float*)d_out;

    // Workspace layout (4 B elements):
    //   buf0[3.2M] | buf1[3.2M] | counts[100000] | row_ptr[100004] |
    //   cursor[100000] | blocksums[128] | epack[1.6M int2]    total ~40 MB
    float* buf0      = (float*)d_ws;
    float* buf1      = buf0 + (size_t)N_NODES * D_IN;
    int*   counts    = (int*)(buf1 + (size_t)N_NODES * D_IN);
    int*   row_ptr   = counts + N_NODES;
    int*   cursor    = row_ptr + (N_NODES + 4);
    int*   blocksums = cursor + N_NODES;
    int2*  epack     = (int2*)(blocksums + 128);

    const int threads = 256;
    const int eblocks = (N_EDGES + threads - 1) / threads;

    // --- CSR build ---
    hipMemsetAsync(counts, 0, N_NODES * sizeof(int), stream);
    count_rows<<<eblocks, threads, 0, stream>>>(erow, counts);
    block_reduce<<<SCAN_BLOCKS, SCAN_T, 0, stream>>>(counts, blocksums);
    scan_blocksums<<<1, 128, 0, stream>>>(blocksums);
    fill_rowptr<<<SCAN_BLOCKS, SCAN_T, 0, stream>>>(counts, blocksums, row_ptr, cursor);
    build_csr<<<eblocks, threads, 0, stream>>>(erow, ecol, eval_, cursor, epack);

    // --- 4 hops of row-gather SpMM (ping-pong) ---
    const int rows_per_block = threads / 32;  // 8
    const int sblocks = (N_NODES + rows_per_block - 1) / rows_per_block;
    const float* cur = x;
    for (int hop = 0; hop < 4; ++hop) {
        float* dst = (hop & 1) ? buf1 : buf0;
        spmm_csr<<<sblocks, threads, 0, stream>>>(row_ptr, epack, cur, dst);
        cur = dst;
    }

    // --- final linear ---
    const int lin_blocks = (N_NODES + 3) / 4;
    linear_bias<<<lin_blocks, 256, 0, stream>>>(cur, W, b, out);
}